// Round 3
// baseline (137.320 us; speedup 1.0000x reference)
//
#include <hip/hip_runtime.h>
#include <hip/hip_bf16.h>

#define BB 16
#define TT 2048
#define CC 68
#define HH 64
#define PP 40   // P row stride in shorts (32 kv + 8 pad; 80 B keeps b128 rows 16B-aligned)

typedef short short8 __attribute__((ext_vector_type(8)));
typedef float floatx4 __attribute__((ext_vector_type(4)));

static __device__ __forceinline__ unsigned short f2bf(float f) {
    union { float f; unsigned u; } v; v.f = f;
    unsigned r = v.u + 0x7fffu + ((v.u >> 16) & 1u);
    return (unsigned short)(r >> 16);
}
static __device__ __forceinline__ unsigned pk2(float a, float b) {
    unsigned ua = __builtin_bit_cast(unsigned, a) + 0x8000u;
    unsigned ub = __builtin_bit_cast(unsigned, b) + 0x8000u;
    return (ua >> 16) | (ub & 0xffff0000u);
}

// ---------------- Kernel 0: W prep ----------------
__global__ __launch_bounds__(256) void prep_w(
        const float* __restrict__ Wk, const float* __restrict__ Wq,
        const float* __restrict__ Wv, unsigned short* __restrict__ Wt) {
    int idx = blockIdx.x * 256 + threadIdx.x;
    if (idx >= 192 * 96) return;
    int n = idx / 96, c = idx - n * 96;
    float v = 0.f;
    if (c < CC) {
        if (n < 64)       v = Wk[c * 64 + n];
        else if (n < 128) v = Wq[c * 64 + (n - 64)] * 0.18033688011112042f; // 0.125*log2e
        else              v = Wv[c * 64 + (n - 128)];
    }
    Wt[idx] = f2bf(v);
}

// ---------------- Kernel 1: QKV projection via MFMA ----------------
__global__ __launch_bounds__(256) void qkv_kernel(
        const float* __restrict__ x, const unsigned short* __restrict__ Wt,
        unsigned short* __restrict__ Qb, unsigned short* __restrict__ Kb,
        unsigned short* __restrict__ Vt) {
    __shared__ unsigned short xs[64 * 104];
    __shared__ unsigned short wl[192 * 104];

    int tid = threadIdx.x;
    int wave = tid >> 6, lane = tid & 63, quad = lane >> 4, l15 = lane & 15;
    size_t row0 = (size_t)blockIdx.x * 64;
    int b = (int)(row0 >> 11), t0 = (int)(row0 & 2047);

    // x: 64 rows x 68 f32 = 1088 contiguous float4; convert+pack to bf16x4
    const float4* xsrc4 = (const float4*)(x + row0 * CC);
    for (int i = tid; i < 1088; i += 256) {
        float4 xv = xsrc4[i];
        int r = i / 17, c4 = i - r * 17;
        uint2 w;
        w.x = (unsigned)f2bf(xv.x) | ((unsigned)f2bf(xv.y) << 16);
        w.y = (unsigned)f2bf(xv.z) | ((unsigned)f2bf(xv.w) << 16);
        *(uint2*)&xs[r * 104 + c4 * 4] = w;
    }
    for (int i = tid; i < 64 * 28; i += 256) {   // zero pad c in [68,96)
        int r = i / 28, c = 68 + (i - r * 28);
        xs[r * 104 + c] = 0;
    }
    for (int i = 0; i < 9; ++i) {                // W: 192*12 16B chunks
        int ci = i * 256 + tid;
        int r = ci / 12, c = ci - r * 12;
        *(short8*)&wl[r * 104 + c * 8] = *(const short8*)&Wt[r * 96 + c * 8];
    }
    __syncthreads();

    short8 a[3];
    #pragma unroll
    for (int cs = 0; cs < 3; ++cs)
        a[cs] = *(const short8*)&xs[(wave * 16 + l15) * 104 + cs * 32 + quad * 8];

    for (int nt = 0; nt < 12; ++nt) {
        floatx4 acc = (floatx4){0.f, 0.f, 0.f, 0.f};
        #pragma unroll
        for (int cs = 0; cs < 3; ++cs) {
            short8 bf = *(const short8*)&wl[(nt * 16 + l15) * 104 + cs * 32 + quad * 8];
            acc = __builtin_amdgcn_mfma_f32_16x16x32_bf16(a[cs], bf, acc, 0, 0, 0);
        }
        if (nt < 8) {
            unsigned short* dst = (nt < 4) ? Kb : Qb;
            int h = (nt & 3) * 16 + l15;
            #pragma unroll
            for (int r = 0; r < 4; ++r)
                dst[(row0 + wave * 16 + quad * 4 + r) * 64 + h] = f2bf(acc[r]);
        } else {
            int h = (nt - 8) * 16 + l15;
            int t = t0 + wave * 16 + quad * 4;
            uint2 v2; v2.x = pk2(acc[0], acc[1]); v2.y = pk2(acc[2], acc[3]);
            *(uint2*)&Vt[((size_t)(b * 64 + h)) * TT + t] = v2;
        }
    }
}

// ---------------- Kernel 2: flash attention, barrier-free K-loop ----------------
// 512 WGs x 256 thr. wave = (half = w>>1 over kv, qh = w&1 over 32-q block).
// K/V fragments loaded straight to registers (no intra-wave reuse -> no LDS),
// double-buffered; LDS only for the P layout round-trip (wave-private) and combine.
__global__ __launch_bounds__(256) void attn_kernel(
        const unsigned short* __restrict__ Qb,
        const unsigned short* __restrict__ Kb,
        const unsigned short* __restrict__ Vt,
        float* __restrict__ out) {
    __shared__ union { unsigned short Ps[4][32 * PP]; float accL[64][66]; } u;
    __shared__ float lL[2][64];

    int tid = threadIdx.x;
    int wave = tid >> 6, lane = tid & 63, quad = lane >> 4, l15 = lane & 15;
    int half = wave >> 1, qh = wave & 1;
    int id = blockIdx.x;
    int b = id & 15, qblk = id >> 4;          // id = qblk*16 + b -> batch pins to XCD id%8
    int q0 = qblk * 64 + qh * 32;
    unsigned short* ps = u.Ps[wave];

    // Q fragments (B-operand of S^T): Q[q=qs*16+l15][h=kh*32+quad*8+j]
    short8 qf[2][2];
    #pragma unroll
    for (int qs = 0; qs < 2; ++qs)
        #pragma unroll
        for (int kh = 0; kh < 2; ++kh)
            qf[qs][kh] = *(const short8*)&Qb[((size_t)(b * TT + q0 + qs * 16 + l15)) * 64
                                             + kh * 32 + quad * 8];

    // per-lane K/V fragment pointers (tile 0 of this wave's kv half)
    const unsigned short* kp[2][2];
    const unsigned short* vp[4];
    {
        size_t kOff = ((size_t)(b * TT + half * 1024)) * 64;
        #pragma unroll
        for (int ks = 0; ks < 2; ++ks)
            #pragma unroll
            for (int kh = 0; kh < 2; ++kh)
                kp[ks][kh] = Kb + kOff + (ks * 16 + l15) * 64 + kh * 32 + quad * 8;
        size_t vOff = (size_t)b * 64 * TT + half * 1024;
        #pragma unroll
        for (int hb = 0; hb < 4; ++hb)
            vp[hb] = Vt + vOff + (size_t)(hb * 16 + l15) * TT + quad * 8;
    }

    floatx4 acc[2][4];
    float lpart[2] = {0.f, 0.f};
    #pragma unroll
    for (int qs = 0; qs < 2; ++qs)
        #pragma unroll
        for (int hb = 0; hb < 4; ++hb) acc[qs][hb] = (floatx4){0.f, 0.f, 0.f, 0.f};

    auto loadKV = [&](short8 (&kf)[2][2], short8 (&vf)[4], int it) {
        #pragma unroll
        for (int ks = 0; ks < 2; ++ks)
            #pragma unroll
            for (int kh = 0; kh < 2; ++kh)
                kf[ks][kh] = *(const short8*)(kp[ks][kh] + it * 2048);  // 32 rows * 64
        #pragma unroll
        for (int hb = 0; hb < 4; ++hb)
            vf[hb] = *(const short8*)(vp[hb] + it * 32);
    };

    auto step = [&](short8 (&kf)[2][2], short8 (&vf)[4],
                    short8 (&kfn)[2][2], short8 (&vfn)[4], int itn) {
        loadKV(kfn, vfn, itn);   // prefetch next tile (vmcnt waits land next step)

        floatx4 s[2][2];
        #pragma unroll
        for (int qs = 0; qs < 2; ++qs)
            #pragma unroll
            for (int ks = 0; ks < 2; ++ks) {
                floatx4 z = (floatx4){0.f, 0.f, 0.f, 0.f};
                z = __builtin_amdgcn_mfma_f32_16x16x32_bf16(kf[ks][0], qf[qs][0], z, 0, 0, 0);
                z = __builtin_amdgcn_mfma_f32_16x16x32_bf16(kf[ks][1], qf[qs][1], z, 0, 0, 0);
                s[qs][ks] = z;
            }

        #pragma unroll
        for (int qs = 0; qs < 2; ++qs) {
            float lp = 0.f;
            #pragma unroll
            for (int ks = 0; ks < 2; ++ks) {
                float e0 = __builtin_amdgcn_exp2f(s[qs][ks][0]);
                float e1 = __builtin_amdgcn_exp2f(s[qs][ks][1]);
                float e2 = __builtin_amdgcn_exp2f(s[qs][ks][2]);
                float e3 = __builtin_amdgcn_exp2f(s[qs][ks][3]);
                lp += (e0 + e1) + (e2 + e3);
                uint2 w; w.x = pk2(e0, e1); w.y = pk2(e2, e3);
                *(uint2*)&ps[(qs * 16 + l15) * PP + ks * 16 + quad * 4] = w;
            }
            lpart[qs] += lp;
        }

        short8 pf[2];
        #pragma unroll
        for (int qs = 0; qs < 2; ++qs)
            pf[qs] = *(const short8*)&ps[(qs * 16 + l15) * PP + quad * 8];
        #pragma unroll
        for (int qs = 0; qs < 2; ++qs)
            #pragma unroll
            for (int hb = 0; hb < 4; ++hb)
                acc[qs][hb] = __builtin_amdgcn_mfma_f32_16x16x32_bf16(pf[qs], vf[hb], acc[qs][hb], 0, 0, 0);
    };

    short8 kfA[2][2], vfA[4], kfB[2][2], vfB[4];
    loadKV(kfA, vfA, 0);
    for (int it2 = 0; it2 < 16; ++it2) {
        int n1 = 2 * it2 + 1;
        int n2 = (2 * it2 + 2 < 32) ? 2 * it2 + 2 : 31;   // clamped dead prefetch on last
        step(kfA, vfA, kfB, vfB, n1);
        step(kfB, vfB, kfA, vfA, n2);
    }

    // l: sum across quads
    #pragma unroll
    for (int qs = 0; qs < 2; ++qs) {
        float v = lpart[qs];
        v += __shfl_xor(v, 16);
        v += __shfl_xor(v, 32);
        lpart[qs] = v;
    }
    if (quad == 0) {
        lL[half][qh * 32 + l15]      = lpart[0];
        lL[half][qh * 32 + 16 + l15] = lpart[1];
    }
    __syncthreads();   // all Ps reads done; lL visible

    if (half == 1) {
        #pragma unroll
        for (int qs = 0; qs < 2; ++qs)
            #pragma unroll
            for (int hb = 0; hb < 4; ++hb)
                #pragma unroll
                for (int r = 0; r < 4; ++r)
                    u.accL[qh * 32 + qs * 16 + quad * 4 + r][hb * 16 + l15] = acc[qs][hb][r];
    }
    __syncthreads();

    if (half == 0) {
        #pragma unroll
        for (int qs = 0; qs < 2; ++qs) {
            float rl[4];
            #pragma unroll
            for (int r = 0; r < 4; ++r) {
                int qw = qh * 32 + qs * 16 + quad * 4 + r;
                rl[r] = 1.0f / (lL[0][qw] + lL[1][qw]);
            }
            #pragma unroll
            for (int hb = 0; hb < 4; ++hb)
                #pragma unroll
                for (int r = 0; r < 4; ++r) {
                    int qw = qh * 32 + qs * 16 + quad * 4 + r;
                    float tot = acc[qs][hb][r] + u.accL[qw][hb * 16 + l15];
                    out[((size_t)(b * TT + qblk * 64 + qw)) * 64 + hb * 16 + l15] = tot * rl[r];
                }
        }
    }
}

extern "C" void kernel_launch(void* const* d_in, const int* in_sizes, int n_in,
                              void* d_out, int out_size, void* d_ws, size_t ws_size,
                              hipStream_t stream) {
    const float* x  = (const float*)d_in[0];
    const float* Wk = (const float*)d_in[1];
    const float* Wq = (const float*)d_in[2];
    const float* Wv = (const float*)d_in[3];

    unsigned short* Qb = (unsigned short*)d_ws;
    unsigned short* Kb = Qb + (size_t)BB * TT * HH;
    unsigned short* Vt = Kb + (size_t)BB * TT * HH;
    unsigned short* Wt = Vt + (size_t)BB * TT * HH;
    float* out = (float*)d_out;

    prep_w<<<dim3(72), dim3(256), 0, stream>>>(Wk, Wq, Wv, Wt);
    qkv_kernel<<<dim3(BB * TT / 64), dim3(256), 0, stream>>>(x, Wt, Qb, Kb, Vt);
    attn_kernel<<<dim3(BB * (TT / 64)), dim3(256), 0, stream>>>(Qb, Kb, Vt, out);
}

// Round 4
// 110.028 us; speedup vs baseline: 1.2480x; 1.2480x over previous
//
#include <hip/hip_runtime.h>
#include <hip/hip_bf16.h>

#define BB 16
#define TT 2048
#define CC 68
#define HH 64
#define PP 40   // P row stride in shorts (32 kv + 8 pad; 80 B keeps b128 rows 16B-aligned)

typedef short short8 __attribute__((ext_vector_type(8)));
typedef float floatx4 __attribute__((ext_vector_type(4)));

static __device__ __forceinline__ unsigned short f2bf(float f) {
    union { float f; unsigned u; } v; v.f = f;
    unsigned r = v.u + 0x7fffu + ((v.u >> 16) & 1u);
    return (unsigned short)(r >> 16);
}
static __device__ __forceinline__ unsigned pk2(float a, float b) {
    unsigned ua = __builtin_bit_cast(unsigned, a) + 0x8000u;
    unsigned ub = __builtin_bit_cast(unsigned, b) + 0x8000u;
    return (ua >> 16) | (ub & 0xffff0000u);
}

#define GLD16(gsrc, ldsbase)                                                        \
    __builtin_amdgcn_global_load_lds(                                               \
        (const __attribute__((address_space(1))) unsigned int*)(gsrc),              \
        (__attribute__((address_space(3))) unsigned int*)(ldsbase), 16, 0, 0)

#define WAITV8 asm volatile("s_waitcnt vmcnt(8)" ::: "memory")
#define WAITV0 asm volatile("s_waitcnt vmcnt(0)" ::: "memory")
#define MEMFENCE asm volatile("" ::: "memory")

// ---------------- Kernel 0: W prep ----------------
// Wt[n][c]: n in [0,192) = K|Q|V output column, c in [0,96) zero-padded input dim.
// Q columns pre-scaled by 0.125*log2(e) so attention uses exp2 directly.
__global__ __launch_bounds__(256) void prep_w(
        const float* __restrict__ Wk, const float* __restrict__ Wq,
        const float* __restrict__ Wv, unsigned short* __restrict__ Wt) {
    int idx = blockIdx.x * 256 + threadIdx.x;
    if (idx >= 192 * 96) return;
    int n = idx / 96, c = idx - n * 96;
    float v = 0.f;
    if (c < CC) {
        if (n < 64)       v = Wk[c * 64 + n];
        else if (n < 128) v = Wq[c * 64 + (n - 64)] * 0.18033688011112042f; // 0.125*log2e
        else              v = Wv[c * 64 + (n - 128)];
    }
    Wt[idx] = f2bf(v);
}

// ---------------- Kernel 1: QKV projection, LDS-free ----------------
// 512 blocks x 256 thr; wave w handles 16 x-rows. A-frags direct from x (fp32),
// W B-frags direct from Wt (L2-hot, 2-deep prefetch). No barriers.
__global__ __launch_bounds__(256) void qkv_kernel(
        const float* __restrict__ x, const unsigned short* __restrict__ Wt,
        unsigned short* __restrict__ Qb, unsigned short* __restrict__ Kb,
        unsigned short* __restrict__ Vt) {
    int tid = threadIdx.x;
    int wave = tid >> 6, lane = tid & 63, quad = lane >> 4, l15 = lane & 15;
    size_t row0 = (size_t)blockIdx.x * 64;
    int b = (int)(row0 >> 11), t0 = (int)(row0 & 2047);
    size_t myrow = row0 + wave * 16 + l15;
    const float* xr = x + myrow * CC;

    // A-fragments: x[myrow][c], c = cs*32 + quad*8 .. +7 (c>=68 -> 0)
    short8 a[3];
    union { short8 s8; unsigned u[4]; } t;
    #pragma unroll
    for (int cs = 0; cs < 2; ++cs) {
        float4 f0 = *(const float4*)(xr + cs * 32 + quad * 8);
        float4 f1 = *(const float4*)(xr + cs * 32 + quad * 8 + 4);
        t.u[0] = pk2(f0.x, f0.y); t.u[1] = pk2(f0.z, f0.w);
        t.u[2] = pk2(f1.x, f1.y); t.u[3] = pk2(f1.z, f1.w);
        a[cs] = t.s8;
    }
    {
        t.u[0] = 0; t.u[1] = 0; t.u[2] = 0; t.u[3] = 0;
        if (quad == 0) {
            float4 f = *(const float4*)(xr + 64);
            t.u[0] = pk2(f.x, f.y); t.u[1] = pk2(f.z, f.w);
        }
        a[2] = t.s8;
    }

    // W B-fragments: Wt[n = nt*16+l15][c = cs*32+quad*8 .. +7]
    auto loadW = [&](short8 (&w)[3], int nt) {
        #pragma unroll
        for (int cs = 0; cs < 3; ++cs)
            w[cs] = *(const short8*)&Wt[(nt * 16 + l15) * 96 + cs * 32 + quad * 8];
    };

    short8 wf[2][3];
    loadW(wf[0], 0);
    for (int nt = 0; nt < 12; ++nt) {
        if (nt + 1 < 12) loadW(wf[(nt + 1) & 1], nt + 1);
        floatx4 acc = (floatx4){0.f, 0.f, 0.f, 0.f};
        #pragma unroll
        for (int cs = 0; cs < 3; ++cs)
            acc = __builtin_amdgcn_mfma_f32_16x16x32_bf16(a[cs], wf[nt & 1][cs], acc, 0, 0, 0);

        // D layout: col(l15) = output n-sub, row(quad*4+r) = x-row-sub
        if (nt < 8) {
            unsigned short* dst = (nt < 4) ? Kb : Qb;
            int h = (nt & 3) * 16 + l15;
            #pragma unroll
            for (int r = 0; r < 4; ++r)
                dst[(row0 + wave * 16 + quad * 4 + r) * 64 + h] = f2bf(acc[r]);
        } else {
            int h = (nt - 8) * 16 + l15;
            int tt = t0 + wave * 16 + quad * 4;
            uint2 v2; v2.x = pk2(acc[0], acc[1]); v2.y = pk2(acc[2], acc[3]);
            *(uint2*)&Vt[((size_t)(b * 64 + h)) * TT + tt] = v2;
        }
    }
}

// ---------------- Kernel 2: flash attention ----------------
// 512 WGs x 256 thr; wave = (half = w>>1 over kv, qh = w&1 over 32-q block).
// Wave-PRIVATE double-buffered LDS staging via global_load_lds; manual vmcnt(8)
// waits; ZERO barriers in the K-loop (Ps is wave-private too).
__global__ __launch_bounds__(256) void attn_kernel(
        const unsigned short* __restrict__ Qb,
        const unsigned short* __restrict__ Kb,
        const unsigned short* __restrict__ Vt,
        float* __restrict__ out) {
    __shared__ union {
        unsigned char stg[4][2][8192];   // [wave][buf][ K 4KB | V 4KB ]
        float accL[64][66];              // combine overlay
    } u;
    __shared__ unsigned short Ps[4][32 * PP];
    __shared__ float lL[2][64];

    int tid = threadIdx.x;
    int wave = tid >> 6, lane = tid & 63, quad = lane >> 4, l15 = lane & 15;
    int half = wave >> 1, qh = wave & 1;
    int id = blockIdx.x;
    int b = id & 15, qblk = id >> 4;          // batch pins to XCD (id%8)
    int q0 = qblk * 64 + qh * 32;
    int kbase = half * 1024;
    unsigned short* ps = Ps[wave];

    // Q fragments (B-operand of S^T): Q[q=qs*16+l15][h=kh*32+quad*8+j]
    short8 qf[2][2];
    #pragma unroll
    for (int qs = 0; qs < 2; ++qs)
        #pragma unroll
        for (int kh = 0; kh < 2; ++kh)
            qf[qs][kh] = *(const short8*)&Qb[((size_t)(b * TT + q0 + qs * 16 + l15)) * 64
                                             + kh * 32 + quad * 8];

    floatx4 acc[2][4];
    float lpart[2] = {0.f, 0.f};
    #pragma unroll
    for (int qs = 0; qs < 2; ++qs)
        #pragma unroll
        for (int hb = 0; hb < 4; ++hb) acc[qs][hb] = (floatx4){0.f, 0.f, 0.f, 0.f};

    // stage tile `it` into buf p (8 x 1KB DMA). K chunks swizzled c'=c^(kv&7);
    // V chunks c'=c^((h>>1)&3).
    auto stage = [&](int it, int p) {
        unsigned char* base = u.stg[wave][p];
        int kt = kbase + it * 32;
        #pragma unroll
        for (int i = 0; i < 4; ++i) {
            int ci = i * 64 + lane;
            int kv = ci >> 3, cp = ci & 7, c = cp ^ (kv & 7);
            GLD16(Kb + ((size_t)(b * TT + kt + kv) * 64 + c * 8), base + i * 1024);
        }
        #pragma unroll
        for (int i = 0; i < 4; ++i) {
            int ci = i * 64 + lane;
            int h = ci >> 2, cp = ci & 3, c = cp ^ ((h >> 1) & 3);
            GLD16(Vt + ((size_t)(b * 64 + h) * TT + kt + c * 8), base + 4096 + i * 1024);
        }
    };

    auto compute = [&](int p) {
        const unsigned char* Kbuf = u.stg[wave][p];
        const unsigned char* Vbuf = Kbuf + 4096;

        short8 kf[2][2], vf[4];
        #pragma unroll
        for (int ks = 0; ks < 2; ++ks)
            #pragma unroll
            for (int kh = 0; kh < 2; ++kh) {
                int cp = (kh * 4 + quad) ^ (l15 & 7);
                kf[ks][kh] = *(const short8*)(Kbuf + (ks * 16 + l15) * 128 + cp * 16);
            }
        #pragma unroll
        for (int hb = 0; hb < 4; ++hb) {
            int cp = quad ^ ((l15 >> 1) & 3);
            vf[hb] = *(const short8*)(Vbuf + (hb * 16 + l15) * 64 + cp * 16);
        }

        floatx4 s[2][2];
        #pragma unroll
        for (int qs = 0; qs < 2; ++qs)
            #pragma unroll
            for (int ks = 0; ks < 2; ++ks) {
                floatx4 z = (floatx4){0.f, 0.f, 0.f, 0.f};
                z = __builtin_amdgcn_mfma_f32_16x16x32_bf16(kf[ks][0], qf[qs][0], z, 0, 0, 0);
                z = __builtin_amdgcn_mfma_f32_16x16x32_bf16(kf[ks][1], qf[qs][1], z, 0, 0, 0);
                s[qs][ks] = z;
            }

        #pragma unroll
        for (int qs = 0; qs < 2; ++qs) {
            float lp = 0.f;
            #pragma unroll
            for (int ks = 0; ks < 2; ++ks) {
                float e0 = __builtin_amdgcn_exp2f(s[qs][ks][0]);
                float e1 = __builtin_amdgcn_exp2f(s[qs][ks][1]);
                float e2 = __builtin_amdgcn_exp2f(s[qs][ks][2]);
                float e3 = __builtin_amdgcn_exp2f(s[qs][ks][3]);
                lp += (e0 + e1) + (e2 + e3);
                uint2 w; w.x = pk2(e0, e1); w.y = pk2(e2, e3);
                *(uint2*)&ps[(qs * 16 + l15) * PP + ks * 16 + quad * 4] = w;
            }
            lpart[qs] += lp;
        }

        short8 pf[2];
        #pragma unroll
        for (int qs = 0; qs < 2; ++qs)
            pf[qs] = *(const short8*)&ps[(qs * 16 + l15) * PP + quad * 8];
        #pragma unroll
        for (int qs = 0; qs < 2; ++qs)
            #pragma unroll
            for (int hb = 0; hb < 4; ++hb)
                acc[qs][hb] = __builtin_amdgcn_mfma_f32_16x16x32_bf16(pf[qs], vf[hb], acc[qs][hb], 0, 0, 0);
    };

    stage(0, 0);
    stage(1, 1);
    for (int it = 0; it < 31; ++it) {
        WAITV8;                       // tile `it` landed; tile it+1 still in flight
        compute(it & 1);
        if (it + 2 < 32) { MEMFENCE; stage(it + 2, it & 1); }
    }
    WAITV0;                           // last tile (31)
    compute(1);

    // l: sum across quads
    #pragma unroll
    for (int qs = 0; qs < 2; ++qs) {
        float v = lpart[qs];
        v += __shfl_xor(v, 16);
        v += __shfl_xor(v, 32);
        lpart[qs] = v;
    }
    if (quad == 0) {
        lL[half][qh * 32 + l15]      = lpart[0];
        lL[half][qh * 32 + 16 + l15] = lpart[1];
    }
    __syncthreads();   // staging fully drained (wave vmcnt=0); lL visible

    if (half == 1) {
        #pragma unroll
        for (int qs = 0; qs < 2; ++qs)
            #pragma unroll
            for (int hb = 0; hb < 4; ++hb)
                #pragma unroll
                for (int r = 0; r < 4; ++r)
                    u.accL[qh * 32 + qs * 16 + quad * 4 + r][hb * 16 + l15] = acc[qs][hb][r];
    }
    __syncthreads();

    if (half == 0) {
        #pragma unroll
        for (int qs = 0; qs < 2; ++qs) {
            float rl[4];
            #pragma unroll
            for (int r = 0; r < 4; ++r) {
                int qw = qh * 32 + qs * 16 + quad * 4 + r;
                rl[r] = 1.0f / (lL[0][qw] + lL[1][qw]);
            }
            #pragma unroll
            for (int hb = 0; hb < 4; ++hb)
                #pragma unroll
                for (int r = 0; r < 4; ++r) {
                    int qw = qh * 32 + qs * 16 + quad * 4 + r;
                    float tot = acc[qs][hb][r] + u.accL[qw][hb * 16 + l15];
                    out[((size_t)(b * TT + qblk * 64 + qw)) * 64 + hb * 16 + l15] = tot * rl[r];
                }
        }
    }
}

extern "C" void kernel_launch(void* const* d_in, const int* in_sizes, int n_in,
                              void* d_out, int out_size, void* d_ws, size_t ws_size,
                              hipStream_t stream) {
    const float* x  = (const float*)d_in[0];
    const float* Wk = (const float*)d_in[1];
    const float* Wq = (const float*)d_in[2];
    const float* Wv = (const float*)d_in[3];

    unsigned short* Qb = (unsigned short*)d_ws;
    unsigned short* Kb = Qb + (size_t)BB * TT * HH;
    unsigned short* Vt = Kb + (size_t)BB * TT * HH;
    unsigned short* Wt = Vt + (size_t)BB * TT * HH;
    float* out = (float*)d_out;

    prep_w<<<dim3(72), dim3(256), 0, stream>>>(Wk, Wq, Wv, Wt);
    qkv_kernel<<<dim3(BB * TT / 64), dim3(256), 0, stream>>>(x, Wt, Qb, Kb, Vt);
    attn_kernel<<<dim3(BB * (TT / 64)), dim3(256), 0, stream>>>(Qb, Kb, Vt, out);
}

// Round 5
// 103.317 us; speedup vs baseline: 1.3291x; 1.0650x over previous
//
#include <hip/hip_runtime.h>
#include <hip/hip_bf16.h>

#define BB 16
#define TT 2048
#define CC 68
#define HH 64
#define PP 40   // P row stride in shorts (32 kv + 8 pad; 80 B rows, 16B-aligned)

typedef short short8 __attribute__((ext_vector_type(8)));
typedef float floatx4 __attribute__((ext_vector_type(4)));

static __device__ __forceinline__ unsigned short f2bf(float f) {
    union { float f; unsigned u; } v; v.f = f;
    unsigned r = v.u + 0x7fffu + ((v.u >> 16) & 1u);
    return (unsigned short)(r >> 16);
}
static __device__ __forceinline__ unsigned pk2(float a, float b) {
    unsigned ua = __builtin_bit_cast(unsigned, a) + 0x8000u;
    unsigned ub = __builtin_bit_cast(unsigned, b) + 0x8000u;
    return (ua >> 16) | (ub & 0xffff0000u);
}

#define GLD16(gsrc, ldsbase)                                                        \
    __builtin_amdgcn_global_load_lds(                                               \
        (const __attribute__((address_space(1))) unsigned int*)(gsrc),              \
        (__attribute__((address_space(3))) unsigned int*)(ldsbase), 16, 0, 0)

#define WAITV4 asm volatile("s_waitcnt vmcnt(4)" ::: "memory")
#define WAITV0 asm volatile("s_waitcnt vmcnt(0)" ::: "memory")
#define BAR    asm volatile("s_barrier" ::: "memory")

// ---------------- Kernel 0: W prep ----------------
// Wt[n][c]: n in [0,192) = K|Q|V output column, c in [0,96) zero-padded.
// Q columns pre-scaled by 0.125*log2(e) so attention uses exp2 directly.
__global__ __launch_bounds__(256) void prep_w(
        const float* __restrict__ Wk, const float* __restrict__ Wq,
        const float* __restrict__ Wv, unsigned short* __restrict__ Wt) {
    int idx = blockIdx.x * 256 + threadIdx.x;
    if (idx >= 192 * 96) return;
    int n = idx / 96, c = idx - n * 96;
    float v = 0.f;
    if (c < CC) {
        if (n < 64)       v = Wk[c * 64 + n];
        else if (n < 128) v = Wq[c * 64 + (n - 64)] * 0.18033688011112042f; // 0.125*log2e
        else              v = Wv[c * 64 + (n - 128)];
    }
    Wt[idx] = f2bf(v);
}

// ---------------- Kernel 1: QKV projection, LDS-free ----------------
// 512 blocks x 256 thr; id = rowblk*16 + b (XCD = b%8, matches attn).
// Wave handles 16 x-rows; W B-frags from L2-hot Wt with 2-deep prefetch.
__global__ __launch_bounds__(256) void qkv_kernel(
        const float* __restrict__ x, const unsigned short* __restrict__ Wt,
        unsigned short* __restrict__ Qb, unsigned short* __restrict__ Kb,
        unsigned short* __restrict__ Vt) {
    int tid = threadIdx.x;
    int wave = tid >> 6, lane = tid & 63, quad = lane >> 4, l15 = lane & 15;
    int id = blockIdx.x;
    int b = id & 15, rowblk = id >> 4;
    size_t row0 = (size_t)b * TT + rowblk * 64;
    int t0 = rowblk * 64;
    size_t myrow = row0 + wave * 16 + l15;
    const float* xr = x + myrow * CC;

    // A-fragments: x[myrow][c], c = cs*32 + quad*8 .. +7 (c>=68 -> 0)
    short8 a[3];
    union { short8 s8; unsigned u[4]; } t;
    #pragma unroll
    for (int cs = 0; cs < 2; ++cs) {
        float4 f0 = *(const float4*)(xr + cs * 32 + quad * 8);
        float4 f1 = *(const float4*)(xr + cs * 32 + quad * 8 + 4);
        t.u[0] = pk2(f0.x, f0.y); t.u[1] = pk2(f0.z, f0.w);
        t.u[2] = pk2(f1.x, f1.y); t.u[3] = pk2(f1.z, f1.w);
        a[cs] = t.s8;
    }
    {
        t.u[0] = 0; t.u[1] = 0; t.u[2] = 0; t.u[3] = 0;
        if (quad == 0) {
            float4 f = *(const float4*)(xr + 64);
            t.u[0] = pk2(f.x, f.y); t.u[1] = pk2(f.z, f.w);
        }
        a[2] = t.s8;
    }

    auto loadW = [&](short8 (&w)[3], int nt) {
        #pragma unroll
        for (int cs = 0; cs < 3; ++cs)
            w[cs] = *(const short8*)&Wt[(nt * 16 + l15) * 96 + cs * 32 + quad * 8];
    };

    short8 wf[3][3];
    loadW(wf[0], 0);
    loadW(wf[1], 1);
    #pragma unroll
    for (int nt = 0; nt < 12; ++nt) {
        if (nt + 2 < 12) loadW(wf[(nt + 2) % 3], nt + 2);
        floatx4 acc = (floatx4){0.f, 0.f, 0.f, 0.f};
        #pragma unroll
        for (int cs = 0; cs < 3; ++cs)
            acc = __builtin_amdgcn_mfma_f32_16x16x32_bf16(a[cs], wf[nt % 3][cs], acc, 0, 0, 0);

        if (nt < 8) {
            unsigned short* dst = (nt < 4) ? Kb : Qb;
            int h = (nt & 3) * 16 + l15;
            #pragma unroll
            for (int r = 0; r < 4; ++r)
                dst[(row0 + wave * 16 + quad * 4 + r) * 64 + h] = f2bf(acc[r]);
        } else {
            int h = (nt - 8) * 16 + l15;
            int tt = t0 + wave * 16 + quad * 4;
            uint2 v2; v2.x = pk2(acc[0], acc[1]); v2.y = pk2(acc[2], acc[3]);
            *(uint2*)&Vt[((size_t)(b * 64 + h)) * TT + tt] = v2;
        }
    }
}

// ---------------- Kernel 2: flash attention, shared staging, 1 barrier/iter ----------------
// 256 WGs x 512 thr (8 waves). id = qblk*16 + b. Wave = (half = w>>2 over kv,
// qh = w&3 over 32-q strips of a 128-q tile). Per half: wave qh=0 stages K,
// qh=1 stages V (global_load_lds, triple-buffered). Producers wait vmcnt(4) --
// DMA queue never drains; ONE s_barrier per iter.
__global__ __launch_bounds__(512, 2) void attn_kernel(
        const unsigned short* __restrict__ Qb,
        const unsigned short* __restrict__ Kb,
        const unsigned short* __restrict__ Vt,
        float* __restrict__ out) {
    __shared__ union {
        unsigned char stg[2][3][8192];   // [half][buf][ K 4KB | V 4KB ]
        float accL[128][66];             // combine overlay
    } u;
    __shared__ unsigned short Ps[8][32 * PP];
    __shared__ float lL[2][128];

    int tid = threadIdx.x;
    int wave = tid >> 6, lane = tid & 63, quad = lane >> 4, l15 = lane & 15;
    int half = wave >> 2, qh = wave & 3;
    int id = blockIdx.x;
    int b = id & 15, qblk = id >> 4;          // XCD = b%8 (matches qkv writes)
    int q0 = qblk * 128 + qh * 32;
    int kbase = half * 1024;
    unsigned short* ps = Ps[wave];

    // Q fragments (B-operand of S^T): Q[q=qs*16+l15][h=kh*32+quad*8+j]
    short8 qf[2][2];
    #pragma unroll
    for (int qs = 0; qs < 2; ++qs)
        #pragma unroll
        for (int kh = 0; kh < 2; ++kh)
            qf[qs][kh] = *(const short8*)&Qb[((size_t)(b * TT + q0 + qs * 16 + l15)) * 64
                                             + kh * 32 + quad * 8];

    floatx4 acc[2][4];
    float lpart[2] = {0.f, 0.f};
    #pragma unroll
    for (int qs = 0; qs < 2; ++qs)
        #pragma unroll
        for (int hb = 0; hb < 4; ++hb) acc[qs][hb] = (floatx4){0.f, 0.f, 0.f, 0.f};

    // stage tile `it` into buf p. K swizzle c'=c^(kv&7); V swizzle c'=c^((h>>1)&3).
    auto stage = [&](int it, int p) {
        int kt = kbase + it * 32;
        if (qh == 0) {
            unsigned char* base = u.stg[half][p];
            #pragma unroll
            for (int i = 0; i < 4; ++i) {
                int ci = i * 64 + lane;
                int kv = ci >> 3, cp = ci & 7, c = cp ^ (kv & 7);
                GLD16(Kb + ((size_t)(b * TT + kt + kv) * 64 + c * 8), base + i * 1024);
            }
        } else if (qh == 1) {
            unsigned char* base = u.stg[half][p] + 4096;
            #pragma unroll
            for (int i = 0; i < 4; ++i) {
                int ci = i * 64 + lane;
                int h = ci >> 2, cp = ci & 3, c = cp ^ ((h >> 1) & 3);
                GLD16(Vt + ((size_t)(b * 64 + h) * TT + kt + c * 8), base + i * 1024);
            }
        }
    };

    auto compute = [&](int p) {
        const unsigned char* Kbuf = u.stg[half][p];
        const unsigned char* Vbuf = Kbuf + 4096;

        short8 kf[2][2], vf[4];
        #pragma unroll
        for (int ks = 0; ks < 2; ++ks)
            #pragma unroll
            for (int kh = 0; kh < 2; ++kh) {
                int cp = (kh * 4 + quad) ^ (l15 & 7);
                kf[ks][kh] = *(const short8*)(Kbuf + (ks * 16 + l15) * 128 + cp * 16);
            }
        #pragma unroll
        for (int hb = 0; hb < 4; ++hb) {
            int cp = quad ^ ((l15 >> 1) & 3);
            vf[hb] = *(const short8*)(Vbuf + (hb * 16 + l15) * 64 + cp * 16);
        }

        floatx4 s[2][2];
        #pragma unroll
        for (int qs = 0; qs < 2; ++qs)
            #pragma unroll
            for (int ks = 0; ks < 2; ++ks) {
                floatx4 z = (floatx4){0.f, 0.f, 0.f, 0.f};
                z = __builtin_amdgcn_mfma_f32_16x16x32_bf16(kf[ks][0], qf[qs][0], z, 0, 0, 0);
                z = __builtin_amdgcn_mfma_f32_16x16x32_bf16(kf[ks][1], qf[qs][1], z, 0, 0, 0);
                s[qs][ks] = z;
            }

        #pragma unroll
        for (int qs = 0; qs < 2; ++qs) {
            float lp = 0.f;
            #pragma unroll
            for (int ks = 0; ks < 2; ++ks) {
                float e0 = __builtin_amdgcn_exp2f(s[qs][ks][0]);
                float e1 = __builtin_amdgcn_exp2f(s[qs][ks][1]);
                float e2 = __builtin_amdgcn_exp2f(s[qs][ks][2]);
                float e3 = __builtin_amdgcn_exp2f(s[qs][ks][3]);
                lp += (e0 + e1) + (e2 + e3);
                uint2 w; w.x = pk2(e0, e1); w.y = pk2(e2, e3);
                *(uint2*)&ps[(qs * 16 + l15) * PP + ks * 16 + quad * 4] = w;
            }
            lpart[qs] += lp;
        }

        short8 pf[2];
        #pragma unroll
        for (int qs = 0; qs < 2; ++qs)
            pf[qs] = *(const short8*)&ps[(qs * 16 + l15) * PP + quad * 8];
        #pragma unroll
        for (int qs = 0; qs < 2; ++qs)
            #pragma unroll
            for (int hb = 0; hb < 4; ++hb)
                acc[qs][hb] = __builtin_amdgcn_mfma_f32_16x16x32_bf16(pf[qs], vf[hb], acc[qs][hb], 0, 0, 0);
    };

    stage(0, 0);
    stage(1, 1);
    for (int it = 0; it < 32; ++it) {
        if (qh < 2) {
            if (it < 31) { WAITV4; } else { WAITV0; }   // tile `it` landed, it+1 in flight
        }
        BAR;                                            // tile visible WG-wide
        if (it + 2 < 32) stage(it + 2, (it + 2) % 3);   // overwrites buf read at it-1 (done)
        compute(it % 3);
    }

    // l: sum across quads
    #pragma unroll
    for (int qs = 0; qs < 2; ++qs) {
        float v = lpart[qs];
        v += __shfl_xor(v, 16);
        v += __shfl_xor(v, 32);
        lpart[qs] = v;
    }
    if (quad == 0) {
        lL[half][qh * 32 + l15]      = lpart[0];
        lL[half][qh * 32 + 16 + l15] = lpart[1];
    }
    __syncthreads();   // full drain OK here (epilogue); lL visible

    if (half == 1) {
        #pragma unroll
        for (int qs = 0; qs < 2; ++qs)
            #pragma unroll
            for (int hb = 0; hb < 4; ++hb)
                #pragma unroll
                for (int r = 0; r < 4; ++r)
                    u.accL[qh * 32 + qs * 16 + quad * 4 + r][hb * 16 + l15] = acc[qs][hb][r];
    }
    __syncthreads();

    if (half == 0) {
        #pragma unroll
        for (int qs = 0; qs < 2; ++qs) {
            float rl[4];
            #pragma unroll
            for (int r = 0; r < 4; ++r) {
                int qw = qh * 32 + qs * 16 + quad * 4 + r;
                rl[r] = 1.0f / (lL[0][qw] + lL[1][qw]);
            }
            #pragma unroll
            for (int hb = 0; hb < 4; ++hb)
                #pragma unroll
                for (int r = 0; r < 4; ++r) {
                    int qw = qh * 32 + qs * 16 + quad * 4 + r;
                    float tot = acc[qs][hb][r] + u.accL[qw][hb * 16 + l15];
                    out[((size_t)(b * TT + qblk * 128 + qw)) * 64 + hb * 16 + l15] = tot * rl[r];
                }
        }
    }
}

extern "C" void kernel_launch(void* const* d_in, const int* in_sizes, int n_in,
                              void* d_out, int out_size, void* d_ws, size_t ws_size,
                              hipStream_t stream) {
    const float* x  = (const float*)d_in[0];
    const float* Wk = (const float*)d_in[1];
    const float* Wq = (const float*)d_in[2];
    const float* Wv = (const float*)d_in[3];

    unsigned short* Qb = (unsigned short*)d_ws;
    unsigned short* Kb = Qb + (size_t)BB * TT * HH;
    unsigned short* Vt = Kb + (size_t)BB * TT * HH;
    unsigned short* Wt = Vt + (size_t)BB * TT * HH;
    float* out = (float*)d_out;

    prep_w<<<dim3(72), dim3(256), 0, stream>>>(Wk, Wq, Wv, Wt);
    qkv_kernel<<<dim3(BB * TT / 64), dim3(256), 0, stream>>>(x, Wt, Qb, Kb, Vt);
    attn_kernel<<<dim3(BB * (TT / 128)), dim3(512), 0, stream>>>(Qb, Kb, Vt, out);
}